// Round 5
// baseline (41.272 us; speedup 1.0000x reference)
//
#include <hip/hip_runtime.h>
#include <hip/hip_bf16.h>

// Siren fused, zero-LDS: swapped-operand MFMA (C = W^T @ data -> [chan][point]).
// L0's C/D layout (lane (g,c16) holds chans {4g+r, 16+4g+r} of point c16) is
// itself a valid B-fragment slot map, so the activated L0 output feeds L1's
// MFMA directly in-lane (kappa1 baked into W1 fragments). No LDS, no barriers,
// no cross-lane traffic except the final 2-shuffle output reduce.

typedef short short8 __attribute__((ext_vector_type(8)));
typedef float f32x4 __attribute__((ext_vector_type(4)));

#define THREADS 256
#define INV2PI 0.15915494309189535f

__device__ __forceinline__ unsigned packbf(float lo, float hi) {
    union { __hip_bfloat162 h; unsigned u; } v;
    v.h = __float22bfloat162_rn(make_float2(lo, hi));
    return v.u;
}

// sin(h radians). v_sin_f32 accepts revolutions in [-256, 256]; |h|/2pi <= ~2 here.
__device__ __forceinline__ float sinact(float h) {
    return __builtin_amdgcn_sinf(h * INV2PI);
}

// ---- bake per-lane A fragments (W^T) ----
// ws (uint4): [0..255]   W0^T frags, id = s*2+cb
//             [256..383] W1^T frags, id = 4+cb   (kappa1(g,e) = e<4 ? 4g+e : 16+4g+e-4)
//             [384..511] W2 per-lane float4 pair {W2[4g+r]}, {W2[16+4g+r]}
__global__ void build_frags(const float* __restrict__ W0,
                            const float* __restrict__ W1,
                            const float* __restrict__ W2,
                            uint4* __restrict__ ws) {
    int l = threadIdx.x;
    if (l >= 64) return;
    int g = l >> 4, c16 = l & 15;
    int d = g & 1, basej = 6 * (g >> 1);

    // kappa0(g,s,e): s0: e0..5 sin j=basej+e, e6..7 cos j=basej+e-6
    //               s1: e0..3 cos j=basej+2+e, e4..7 zero
#pragma unroll
    for (int s = 0; s < 2; ++s)
#pragma unroll
        for (int cb = 0; cb < 2; ++cb) {
            float ev[8];
#pragma unroll
            for (int e = 0; e < 8; ++e) {
                int k;
                if (s == 0) k = (e < 6) ? (d * 24 + basej + e) : (d * 24 + 12 + basej + e - 6);
                else        k = (e < 4) ? (d * 24 + 12 + basej + 2 + e) : -1;
                ev[e] = (k >= 0) ? W0[k * 32 + 16 * cb + c16] : 0.0f;  // A[i=c16][k]
            }
            ws[(s * 2 + cb) * 64 + l] = make_uint4(packbf(ev[0], ev[1]), packbf(ev[2], ev[3]),
                                                   packbf(ev[4], ev[5]), packbf(ev[6], ev[7]));
        }

    // W1^T fragments with kappa1 matching L0's C/D ownership pattern
#pragma unroll
    for (int cb = 0; cb < 2; ++cb) {
        float ev[8];
#pragma unroll
        for (int e = 0; e < 8; ++e) {
            int k = (e < 4) ? (4 * g + e) : (16 + 4 * g + (e - 4));
            ev[e] = W1[k * 32 + 16 * cb + c16];
        }
        ws[(4 + cb) * 64 + l] = make_uint4(packbf(ev[0], ev[1]), packbf(ev[2], ev[3]),
                                           packbf(ev[4], ev[5]), packbf(ev[6], ev[7]));
    }

    float4* w2v = (float4*)(ws + 384);
    w2v[2 * l]     = make_float4(W2[4 * g + 0], W2[4 * g + 1], W2[4 * g + 2], W2[4 * g + 3]);
    w2v[2 * l + 1] = make_float4(W2[16 + 4 * g + 0], W2[16 + 4 * g + 1],
                                 W2[16 + 4 * g + 2], W2[16 + 4 * g + 3]);
}

__global__ __launch_bounds__(THREADS, 5) void siren_mfma_kernel(
    const float2* __restrict__ x,
    const uint4* __restrict__ wf,
    float* __restrict__ out,
    int n)
{
    const int lane = threadIdx.x & 63;
    const int wid = threadIdx.x >> 6;
    const int g = lane >> 4, c16 = lane & 15;
    const int p0 = blockIdx.x * THREADS + wid * 64;
    if (p0 >= n) return;

    // ---- per-lane weight fragments ----
    union U { uint4 u; short8 v; };
    short8 a0[2][2], a1[2];
#pragma unroll
    for (int s = 0; s < 2; ++s)
#pragma unroll
        for (int cb = 0; cb < 2; ++cb) { U t; t.u = wf[(s * 2 + cb) * 64 + lane]; a0[s][cb] = t.v; }
#pragma unroll
    for (int cb = 0; cb < 2; ++cb) { U t; t.u = wf[(4 + cb) * 64 + lane]; a1[cb] = t.v; }
    const float4 w2a = ((const float4*)(wf + 384))[2 * lane];
    const float4 w2b = ((const float4*)(wf + 384))[2 * lane + 1];

    const float sclseed = (g >> 1) ? 32.0f : 0.5f;  // 2^(basej-1), basej in {0,6}
    const bool dsel = (g & 1) != 0;

    float v[4];

#pragma unroll
    for (int m = 0; m < 4; ++m) {
        // ---- enc chain for this lane's (d, j-range) slice of point 16m+c16 ----
        const float2 p = x[p0 + 16 * m + c16];
        const float xd = dsel ? p.y : p.x;
        float sv[6], cv[6];
        float r0 = __builtin_amdgcn_fractf(xd * sclseed);
        sv[0] = __builtin_amdgcn_sinf(r0);
        cv[0] = __builtin_amdgcn_cosf(r0);
#pragma unroll
        for (int j = 1; j < 6; ++j) {
            float t = sv[j - 1] + sv[j - 1];
            sv[j] = t * cv[j - 1];
            cv[j] = fmaf(-t, sv[j - 1], 1.0f);
        }
        union { unsigned u[4]; short8 v; } bs0, bs1;
        bs0.u[0] = packbf(sv[0], sv[1]); bs0.u[1] = packbf(sv[2], sv[3]);
        bs0.u[2] = packbf(sv[4], sv[5]); bs0.u[3] = packbf(cv[0], cv[1]);
        bs1.u[0] = packbf(cv[2], cv[3]); bs1.u[1] = packbf(cv[4], cv[5]);
        bs1.u[2] = 0; bs1.u[3] = 0;

        // ---- layer 0: C[chan][point] ----
        f32x4 acc[2] = {{0.f, 0.f, 0.f, 0.f}, {0.f, 0.f, 0.f, 0.f}};
        acc[0] = __builtin_amdgcn_mfma_f32_16x16x32_bf16(a0[0][0], bs0.v, acc[0], 0, 0, 0);
        acc[1] = __builtin_amdgcn_mfma_f32_16x16x32_bf16(a0[0][1], bs0.v, acc[1], 0, 0, 0);
        acc[0] = __builtin_amdgcn_mfma_f32_16x16x32_bf16(a0[1][0], bs1.v, acc[0], 0, 0, 0);
        acc[1] = __builtin_amdgcn_mfma_f32_16x16x32_bf16(a0[1][1], bs1.v, acc[1], 0, 0, 0);

        // ---- act -> L1 B-fragment directly in-lane (kappa1 = ownership map) ----
        union { unsigned u[4]; short8 v; } fb;
        fb.u[0] = packbf(sinact(acc[0][0]), sinact(acc[0][1]));
        fb.u[1] = packbf(sinact(acc[0][2]), sinact(acc[0][3]));
        fb.u[2] = packbf(sinact(acc[1][0]), sinact(acc[1][1]));
        fb.u[3] = packbf(sinact(acc[1][2]), sinact(acc[1][3]));

        // ---- layer 1 ----
        f32x4 acc1[2] = {{0.f, 0.f, 0.f, 0.f}, {0.f, 0.f, 0.f, 0.f}};
        acc1[0] = __builtin_amdgcn_mfma_f32_16x16x32_bf16(a1[0], fb.v, acc1[0], 0, 0, 0);
        acc1[1] = __builtin_amdgcn_mfma_f32_16x16x32_bf16(a1[1], fb.v, acc1[1], 0, 0, 0);

        // ---- act + W2 partial (chans {4g+r, 16+4g+r} of point 16m+c16) ----
        float vm;
        vm = sinact(acc1[0][0]) * w2a.x;
        vm = fmaf(sinact(acc1[0][1]), w2a.y, vm);
        vm = fmaf(sinact(acc1[0][2]), w2a.z, vm);
        vm = fmaf(sinact(acc1[0][3]), w2a.w, vm);
        vm = fmaf(sinact(acc1[1][0]), w2b.x, vm);
        vm = fmaf(sinact(acc1[1][1]), w2b.y, vm);
        vm = fmaf(sinact(acc1[1][2]), w2b.z, vm);
        vm = fmaf(sinact(acc1[1][3]), w2b.w, vm);
        v[m] = vm;
    }

    // ---- reduce over g (4 lanes hold partials of the same point) ----
#pragma unroll
    for (int m = 0; m < 4; ++m) {
        v[m] += __shfl_xor(v[m], 16, 64);
        v[m] += __shfl_xor(v[m], 32, 64);
    }
    // lane's own output is m = g: point = 16g + c16 = lane
    float ra = (g & 1) ? v[1] : v[0];
    float rb = (g & 1) ? v[3] : v[2];
    out[p0 + lane] = (g & 2) ? rb : ra;
}

extern "C" void kernel_launch(void* const* d_in, const int* in_sizes, int n_in,
                              void* d_out, int out_size, void* d_ws, size_t ws_size,
                              hipStream_t stream) {
    const float2* x = (const float2*)d_in[0];
    const float* W0 = (const float*)d_in[1];
    const float* W1 = (const float*)d_in[2];
    const float* W2 = (const float*)d_in[3];
    float* out = (float*)d_out;
    uint4* ws = (uint4*)d_ws;

    const int n = in_sizes[0] / 2;
    build_frags<<<1, 64, 0, stream>>>(W0, W1, W2, ws);
    const int blocks = (n + THREADS - 1) / THREADS;
    siren_mfma_kernel<<<blocks, THREADS, 0, stream>>>(x, ws, out, n);
}

// Round 6
// 38.806 us; speedup vs baseline: 1.0635x; 1.0635x over previous
//
#include <hip/hip_runtime.h>
#include <hip/hip_bf16.h>

// Siren fused, 32x32x16 MFMA, zero-LDS, double sigma-cancellation:
//   L0: C = W0^T(32x48) @ enc(48x32pts) -> 3 MFMAs, K=48 exact, no pad.
//       Lane (h=lane>>5, q=lane&31) supplies its 24 enc values (dim h, point q)
//       as the B-fragments; A baked with the same k-map.
//   L1: L0's C/D ownership (lane holds chans {c: c&4==4h} of point q) is itself
//       a valid B-fragment map -> act feeds L1 in-lane, kappa1 baked into A1.
//   L2: per-lane 16-chan dot + one shfl_xor(32) + coalesced store.

typedef short short8 __attribute__((ext_vector_type(8)));
typedef float f32x16 __attribute__((ext_vector_type(16)));

#define THREADS 256
#define INV2PI 0.15915494309189535f

__device__ __forceinline__ unsigned packbf(float lo, float hi) {
    union { __hip_bfloat162 h; unsigned u; } v;
    v.h = __float22bfloat162_rn(make_float2(lo, hi));
    return v.u;
}

// sin(h radians); v_sin_f32 takes revolutions, valid to +-256 rev.
__device__ __forceinline__ float sinact(float h) {
    return __builtin_amdgcn_sinf(h * INV2PI);
}

__device__ __forceinline__ f32x16 zero16() {
    f32x16 z;
#pragma unroll
    for (int i = 0; i < 16; ++i) z[i] = 0.0f;
    return z;
}

// ---- bake per-lane A fragments (W^T), 32x32x16 shape ----
// ws (uint4): [0..191]   A0 frags, id t=0..2 : elem e of lane(h,c) = W0[h*24+8t+e][c]
//             [192..319] A1 frags, id t=0..1 : elem e = W1[(e&3)+8*(e>>2)+4h+16t][c]
//             [320..575] W2 per-lane 4x float4: w2v[i] = W2[8i+4h .. +3]
__global__ void build_frags(const float* __restrict__ W0,
                            const float* __restrict__ W1,
                            const float* __restrict__ W2,
                            uint4* __restrict__ ws) {
    int l = threadIdx.x;
    if (l >= 64) return;
    int h = l >> 5, c = l & 31;

#pragma unroll
    for (int t = 0; t < 3; ++t) {
        float ev[8];
#pragma unroll
        for (int e = 0; e < 8; ++e) ev[e] = W0[(h * 24 + 8 * t + e) * 32 + c];
        ws[t * 64 + l] = make_uint4(packbf(ev[0], ev[1]), packbf(ev[2], ev[3]),
                                    packbf(ev[4], ev[5]), packbf(ev[6], ev[7]));
    }
#pragma unroll
    for (int t = 0; t < 2; ++t) {
        float ev[8];
#pragma unroll
        for (int e = 0; e < 8; ++e) {
            int k = (e & 3) + 8 * (e >> 2) + 4 * h + 16 * t;
            ev[e] = W1[k * 32 + c];
        }
        ws[(3 + t) * 64 + l] = make_uint4(packbf(ev[0], ev[1]), packbf(ev[2], ev[3]),
                                          packbf(ev[4], ev[5]), packbf(ev[6], ev[7]));
    }
    float4* w2v = (float4*)(ws + 320);
#pragma unroll
    for (int i = 0; i < 4; ++i)
        w2v[l * 4 + i] = make_float4(W2[8 * i + 4 * h + 0], W2[8 * i + 4 * h + 1],
                                     W2[8 * i + 4 * h + 2], W2[8 * i + 4 * h + 3]);
}

__global__ __launch_bounds__(THREADS, 6) void siren_mfma_kernel(
    const float* __restrict__ xf,     // [N][2] flat
    const uint4* __restrict__ wf,
    float* __restrict__ out,
    int n)
{
    const int lane = threadIdx.x & 63;
    const int wid = threadIdx.x >> 6;
    const int q = lane & 31, h = lane >> 5;
    const int p0 = blockIdx.x * THREADS + wid * 64;
    if (p0 >= n) return;

    union U { uint4 u; short8 v; };
    short8 a0[3], a1[2];
#pragma unroll
    for (int t = 0; t < 3; ++t) { U tt; tt.u = wf[t * 64 + lane]; a0[t] = tt.v; }
#pragma unroll
    for (int t = 0; t < 2; ++t) { U tt; tt.u = wf[(3 + t) * 64 + lane]; a1[t] = tt.v; }
    float4 w2v[4];
#pragma unroll
    for (int i = 0; i < 4; ++i) w2v[i] = ((const float4*)(wf + 320))[lane * 4 + i];

    float vres[2];

#pragma unroll
    for (int b = 0; b < 2; ++b) {
        // ---- enc: dim h of point (p0 + 32b + q), 12 sin + 12 cos ----
        const float xd = xf[(p0 + 32 * b + q) * 2 + h];
        float sv[12], cv[12];
        {
            float r0 = __builtin_amdgcn_fractf(xd * 0.5f);     // j=0 seed
            sv[0] = __builtin_amdgcn_sinf(r0);
            cv[0] = __builtin_amdgcn_cosf(r0);
#pragma unroll
            for (int j = 1; j < 6; ++j) {
                float t = sv[j - 1] + sv[j - 1];
                sv[j] = t * cv[j - 1];
                cv[j] = fmaf(-t, sv[j - 1], 1.0f);
            }
            float r1 = __builtin_amdgcn_fractf(xd * 32.0f);    // j=6 seed
            sv[6] = __builtin_amdgcn_sinf(r1);
            cv[6] = __builtin_amdgcn_cosf(r1);
#pragma unroll
            for (int j = 7; j < 12; ++j) {
                float t = sv[j - 1] + sv[j - 1];
                sv[j] = t * cv[j - 1];
                cv[j] = fmaf(-t, sv[j - 1], 1.0f);
            }
        }

        // ---- B0 fragments: elem(t,e) = enc value idx=8t+e (idx<12: sin, else cos) ----
        union { unsigned u[4]; short8 v; } bf0, bf1, bf2;
        bf0.u[0] = packbf(sv[0], sv[1]);  bf0.u[1] = packbf(sv[2], sv[3]);
        bf0.u[2] = packbf(sv[4], sv[5]);  bf0.u[3] = packbf(sv[6], sv[7]);
        bf1.u[0] = packbf(sv[8], sv[9]);  bf1.u[1] = packbf(sv[10], sv[11]);
        bf1.u[2] = packbf(cv[0], cv[1]);  bf1.u[3] = packbf(cv[2], cv[3]);
        bf2.u[0] = packbf(cv[4], cv[5]);  bf2.u[1] = packbf(cv[6], cv[7]);
        bf2.u[2] = packbf(cv[8], cv[9]);  bf2.u[3] = packbf(cv[10], cv[11]);

        // ---- layer 0: 3 MFMAs, C[32 chan][32 pt] ----
        f32x16 acc = zero16();
        acc = __builtin_amdgcn_mfma_f32_32x32x16_bf16(a0[0], bf0.v, acc, 0, 0, 0);
        acc = __builtin_amdgcn_mfma_f32_32x32x16_bf16(a0[1], bf1.v, acc, 0, 0, 0);
        acc = __builtin_amdgcn_mfma_f32_32x32x16_bf16(a0[2], bf2.v, acc, 0, 0, 0);

        // ---- act -> B1 fragments in-lane (kappa1 = ownership map) ----
        union { unsigned u[4]; short8 v; } b1a, b1b;
#pragma unroll
        for (int i = 0; i < 4; ++i)
            b1a.u[i] = packbf(sinact(acc[2 * i]), sinact(acc[2 * i + 1]));
#pragma unroll
        for (int i = 0; i < 4; ++i)
            b1b.u[i] = packbf(sinact(acc[8 + 2 * i]), sinact(acc[8 + 2 * i + 1]));

        // ---- layer 1: 2 MFMAs ----
        f32x16 acc1 = zero16();
        acc1 = __builtin_amdgcn_mfma_f32_32x32x16_bf16(a1[0], b1a.v, acc1, 0, 0, 0);
        acc1 = __builtin_amdgcn_mfma_f32_32x32x16_bf16(a1[1], b1b.v, acc1, 0, 0, 0);

        // ---- act + W2 dot: reg r holds chan (r&3)+8*(r>>2)+4h -> W2 = w2v[r>>2][r&3] ----
        float s0, s1, s2, s3;
        s0 = sinact(acc1[0]) * w2v[0].x;
        s0 = fmaf(sinact(acc1[1]), w2v[0].y, s0);
        s0 = fmaf(sinact(acc1[2]), w2v[0].z, s0);
        s0 = fmaf(sinact(acc1[3]), w2v[0].w, s0);
        s1 = sinact(acc1[4]) * w2v[1].x;
        s1 = fmaf(sinact(acc1[5]), w2v[1].y, s1);
        s1 = fmaf(sinact(acc1[6]), w2v[1].z, s1);
        s1 = fmaf(sinact(acc1[7]), w2v[1].w, s1);
        s2 = sinact(acc1[8]) * w2v[2].x;
        s2 = fmaf(sinact(acc1[9]), w2v[2].y, s2);
        s2 = fmaf(sinact(acc1[10]), w2v[2].z, s2);
        s2 = fmaf(sinact(acc1[11]), w2v[2].w, s2);
        s3 = sinact(acc1[12]) * w2v[3].x;
        s3 = fmaf(sinact(acc1[13]), w2v[3].y, s3);
        s3 = fmaf(sinact(acc1[14]), w2v[3].z, s3);
        s3 = fmaf(sinact(acc1[15]), w2v[3].w, s3);
        vres[b] = (s0 + s1) + (s2 + s3);
    }

    // ---- cross-half reduce (2 lanes per point) + coalesced store ----
    vres[0] += __shfl_xor(vres[0], 32, 64);
    vres[1] += __shfl_xor(vres[1], 32, 64);
    out[p0 + lane] = h ? vres[1] : vres[0];
}

extern "C" void kernel_launch(void* const* d_in, const int* in_sizes, int n_in,
                              void* d_out, int out_size, void* d_ws, size_t ws_size,
                              hipStream_t stream) {
    const float* xf = (const float*)d_in[0];
    const float* W0 = (const float*)d_in[1];
    const float* W1 = (const float*)d_in[2];
    const float* W2 = (const float*)d_in[3];
    float* out = (float*)d_out;
    uint4* ws = (uint4*)d_ws;

    const int n = in_sizes[0] / 2;
    build_frags<<<1, 64, 0, stream>>>(W0, W1, W2, ws);
    const int blocks = (n + THREADS - 1) / THREADS;
    siren_mfma_kernel<<<blocks, THREADS, 0, stream>>>(xf, ws, out, n);
}

// Round 8
// 35.591 us; speedup vs baseline: 1.1596x; 1.0903x over previous
//
#include <hip/hip_runtime.h>
#include <hip/hip_bf16.h>

// Siren fused, 32x32x16 MFMA, zero-LDS, double sigma-cancellation.
// R8: revert cvt_pk inline asm (R7 NaN; compiler emits HW v_cvt_pk_bf16_f32
// from the scalar-cast path per m240), keep 1/2pi baked into W0/W1 fragments
// (activations are bare v_sin), relax launch_bounds to (256,4) so the
// unrolled b-loop's live set (~110 VGPRs) fits without scratch spills.

typedef short short8 __attribute__((ext_vector_type(8)));
typedef float f32x16 __attribute__((ext_vector_type(16)));

#define THREADS 256
#define INV2PI 0.15915494309189535f

__device__ __forceinline__ unsigned packbf(float lo, float hi) {
    union { __hip_bfloat162 h; unsigned u; } v;
    v.h = __float22bfloat162_rn(make_float2(lo, hi));
    return v.u;
}

__device__ __forceinline__ f32x16 zero16() {
    f32x16 z;
#pragma unroll
    for (int i = 0; i < 16; ++i) z[i] = 0.0f;
    return z;
}

// ---- bake per-lane A fragments (W^T scaled by 1/2pi), 32x32x16 shape ----
// ws (uint4): [0..191]   A0 frags, t=0..2 : elem e of lane(h,c) = W0[h*24+8t+e][c]/2pi
//             [192..319] A1 frags, t=0..1 : elem e = W1[(e&3)+8*(e>>2)+4h+16t][c]/2pi
//             [320..575] W2 per-lane 4x float4: w2v[i] = W2[8i+4h .. +3]
__global__ void build_frags(const float* __restrict__ W0,
                            const float* __restrict__ W1,
                            const float* __restrict__ W2,
                            uint4* __restrict__ ws) {
    int l = threadIdx.x;
    if (l >= 64) return;
    int h = l >> 5, c = l & 31;

#pragma unroll
    for (int t = 0; t < 3; ++t) {
        float ev[8];
#pragma unroll
        for (int e = 0; e < 8; ++e) ev[e] = W0[(h * 24 + 8 * t + e) * 32 + c] * INV2PI;
        ws[t * 64 + l] = make_uint4(packbf(ev[0], ev[1]), packbf(ev[2], ev[3]),
                                    packbf(ev[4], ev[5]), packbf(ev[6], ev[7]));
    }
#pragma unroll
    for (int t = 0; t < 2; ++t) {
        float ev[8];
#pragma unroll
        for (int e = 0; e < 8; ++e) {
            int k = (e & 3) + 8 * (e >> 2) + 4 * h + 16 * t;
            ev[e] = W1[k * 32 + c] * INV2PI;
        }
        ws[(3 + t) * 64 + l] = make_uint4(packbf(ev[0], ev[1]), packbf(ev[2], ev[3]),
                                          packbf(ev[4], ev[5]), packbf(ev[6], ev[7]));
    }
    float4* w2v = (float4*)(ws + 320);
#pragma unroll
    for (int i = 0; i < 4; ++i)
        w2v[l * 4 + i] = make_float4(W2[8 * i + 4 * h + 0], W2[8 * i + 4 * h + 1],
                                     W2[8 * i + 4 * h + 2], W2[8 * i + 4 * h + 3]);
}

__global__ __launch_bounds__(THREADS, 4) void siren_mfma_kernel(
    const float* __restrict__ xf,     // [N][2] flat
    const uint4* __restrict__ wf,
    float* __restrict__ out,
    int n)
{
    const int lane = threadIdx.x & 63;
    const int wid = threadIdx.x >> 6;
    const int q = lane & 31, h = lane >> 5;
    const int p0 = blockIdx.x * THREADS + wid * 64;
    if (p0 >= n) return;

    union U { uint4 u; short8 v; };
    short8 a0[3], a1[2];
#pragma unroll
    for (int t = 0; t < 3; ++t) { U tt; tt.u = wf[t * 64 + lane]; a0[t] = tt.v; }
#pragma unroll
    for (int t = 0; t < 2; ++t) { U tt; tt.u = wf[(3 + t) * 64 + lane]; a1[t] = tt.v; }
    float4 w2v[4];
#pragma unroll
    for (int i = 0; i < 4; ++i) w2v[i] = ((const float4*)(wf + 320))[lane * 4 + i];

    float vres[2];

#pragma unroll
    for (int b = 0; b < 2; ++b) {
        // ---- enc: dim h of point (p0 + 32b + q), 12 sin + 12 cos ----
        const float xd = xf[(p0 + 32 * b + q) * 2 + h];
        float sv[12], cv[12];
        {
            float r0 = __builtin_amdgcn_fractf(xd * 0.5f);     // j=0 seed
            sv[0] = __builtin_amdgcn_sinf(r0);
            cv[0] = __builtin_amdgcn_cosf(r0);
#pragma unroll
            for (int j = 1; j < 6; ++j) {
                float t = sv[j - 1] + sv[j - 1];
                sv[j] = t * cv[j - 1];
                cv[j] = fmaf(-t, sv[j - 1], 1.0f);
            }
            float r1 = __builtin_amdgcn_fractf(xd * 32.0f);    // j=6 seed
            sv[6] = __builtin_amdgcn_sinf(r1);
            cv[6] = __builtin_amdgcn_cosf(r1);
#pragma unroll
            for (int j = 7; j < 12; ++j) {
                float t = sv[j - 1] + sv[j - 1];
                sv[j] = t * cv[j - 1];
                cv[j] = fmaf(-t, sv[j - 1], 1.0f);
            }
        }

        // ---- B0 fragments: elem(t,e) = enc idx 8t+e (idx<12: sin, else cos) ----
        union { unsigned u[4]; short8 v; } bf0, bf1, bf2;
        bf0.u[0] = packbf(sv[0], sv[1]);  bf0.u[1] = packbf(sv[2], sv[3]);
        bf0.u[2] = packbf(sv[4], sv[5]);  bf0.u[3] = packbf(sv[6], sv[7]);
        bf1.u[0] = packbf(sv[8], sv[9]);  bf1.u[1] = packbf(sv[10], sv[11]);
        bf1.u[2] = packbf(cv[0], cv[1]);  bf1.u[3] = packbf(cv[2], cv[3]);
        bf2.u[0] = packbf(cv[4], cv[5]);  bf2.u[1] = packbf(cv[6], cv[7]);
        bf2.u[2] = packbf(cv[8], cv[9]);  bf2.u[3] = packbf(cv[10], cv[11]);

        // ---- layer 0: 3 MFMAs, C[32 chan][32 pt], acc in revolutions ----
        f32x16 acc = zero16();
        acc = __builtin_amdgcn_mfma_f32_32x32x16_bf16(a0[0], bf0.v, acc, 0, 0, 0);
        acc = __builtin_amdgcn_mfma_f32_32x32x16_bf16(a0[1], bf1.v, acc, 0, 0, 0);
        acc = __builtin_amdgcn_mfma_f32_32x32x16_bf16(a0[2], bf2.v, acc, 0, 0, 0);

        // ---- act (bare v_sin) -> B1 fragments in-lane ----
        union { unsigned u[4]; short8 v; } b1a, b1b;
#pragma unroll
        for (int i = 0; i < 4; ++i)
            b1a.u[i] = packbf(__builtin_amdgcn_sinf(acc[2 * i]),
                              __builtin_amdgcn_sinf(acc[2 * i + 1]));
#pragma unroll
        for (int i = 0; i < 4; ++i)
            b1b.u[i] = packbf(__builtin_amdgcn_sinf(acc[8 + 2 * i]),
                              __builtin_amdgcn_sinf(acc[8 + 2 * i + 1]));

        // ---- layer 1: 2 MFMAs, acc1 in revolutions ----
        f32x16 acc1 = zero16();
        acc1 = __builtin_amdgcn_mfma_f32_32x32x16_bf16(a1[0], b1a.v, acc1, 0, 0, 0);
        acc1 = __builtin_amdgcn_mfma_f32_32x32x16_bf16(a1[1], b1b.v, acc1, 0, 0, 0);

        // ---- act + W2 dot: reg r -> chan (r&3)+8*(r>>2)+4h -> w2v[r>>2][r&3] ----
        float s0, s1, s2, s3;
        s0 = __builtin_amdgcn_sinf(acc1[0]) * w2v[0].x;
        s0 = fmaf(__builtin_amdgcn_sinf(acc1[1]), w2v[0].y, s0);
        s0 = fmaf(__builtin_amdgcn_sinf(acc1[2]), w2v[0].z, s0);
        s0 = fmaf(__builtin_amdgcn_sinf(acc1[3]), w2v[0].w, s0);
        s1 = __builtin_amdgcn_sinf(acc1[4]) * w2v[1].x;
        s1 = fmaf(__builtin_amdgcn_sinf(acc1[5]), w2v[1].y, s1);
        s1 = fmaf(__builtin_amdgcn_sinf(acc1[6]), w2v[1].z, s1);
        s1 = fmaf(__builtin_amdgcn_sinf(acc1[7]), w2v[1].w, s1);
        s2 = __builtin_amdgcn_sinf(acc1[8]) * w2v[2].x;
        s2 = fmaf(__builtin_amdgcn_sinf(acc1[9]), w2v[2].y, s2);
        s2 = fmaf(__builtin_amdgcn_sinf(acc1[10]), w2v[2].z, s2);
        s2 = fmaf(__builtin_amdgcn_sinf(acc1[11]), w2v[2].w, s2);
        s3 = __builtin_amdgcn_sinf(acc1[12]) * w2v[3].x;
        s3 = fmaf(__builtin_amdgcn_sinf(acc1[13]), w2v[3].y, s3);
        s3 = fmaf(__builtin_amdgcn_sinf(acc1[14]), w2v[3].z, s3);
        s3 = fmaf(__builtin_amdgcn_sinf(acc1[15]), w2v[3].w, s3);
        vres[b] = (s0 + s1) + (s2 + s3);
    }

    // ---- cross-half reduce (2 lanes per point) + coalesced store ----
    vres[0] += __shfl_xor(vres[0], 32, 64);
    vres[1] += __shfl_xor(vres[1], 32, 64);
    out[p0 + lane] = h ? vres[1] : vres[0];
}

extern "C" void kernel_launch(void* const* d_in, const int* in_sizes, int n_in,
                              void* d_out, int out_size, void* d_ws, size_t ws_size,
                              hipStream_t stream) {
    const float* xf = (const float*)d_in[0];
    const float* W0 = (const float*)d_in[1];
    const float* W1 = (const float*)d_in[2];
    const float* W2 = (const float*)d_in[3];
    float* out = (float*)d_out;
    uint4* ws = (uint4*)d_ws;

    const int n = in_sizes[0] / 2;
    build_frags<<<1, 64, 0, stream>>>(W0, W1, W2, ws);
    const int blocks = (n + THREADS - 1) / THREADS;
    siren_mfma_kernel<<<blocks, THREADS, 0, stream>>>(xf, ws, out, n);
}